// Round 4
// baseline (202.459 us; speedup 1.0000x reference)
//
#include <hip/hip_runtime.h>

// QuantLinearW4A4Tl: M=8192, K=4096, N=4096, R=32
#define M_ 8192
#define K_ 4096
#define N_ 4096
#define R_ 32
#define KP_ (K_ / 2)

// GEMM: 256x128 block tile, BK=64 i8, 4 waves (2x2) of 128x64, mfma 32x32x32,
// 3-deep LDS pipeline (72 KiB static) -> 2 blocks/CU for cross-block overlap.
#define BM 256
#define BN 128
#define BK 64
#define NT 64                 // K_/BK
#define A_TILE 16384          // BM*BK
#define B_TILE 8192           // BN*BK
#define BUF_SZ (A_TILE + B_TILE)   // 24 KiB
#define GRID ((M_ / BM) * (N_ / BN))   // 32*32 = 1024

typedef __attribute__((ext_vector_type(4)))  int    i32x4;
typedef __attribute__((ext_vector_type(16))) int    i32x16;
typedef __attribute__((ext_vector_type(4)))  float  f32x4;
typedef __attribute__((ext_vector_type(16))) float  f32x16;
typedef __attribute__((ext_vector_type(8)))  __bf16 bf16x8;

__device__ __forceinline__ void gload16(const void* g, void* l) {
  __builtin_amdgcn_global_load_lds(
      (const __attribute__((address_space(1))) unsigned int*)g,
      (__attribute__((address_space(3))) unsigned int*)l, 16, 0, 0);
}

__device__ __forceinline__ unsigned nib2(int b) {
  unsigned lo = (unsigned)(((b & 15) ^ 8) - 8) & 0xFFu;
  unsigned hi = (unsigned)((((b >> 4) & 15) ^ 8) - 8) & 0xFFu;
  return lo | (hi << 8);
}

// ---- repack A: granule image [mt(32)][kt(64)][fm(8)][ks(2)][lane(64)][16B] ----
// granule-lane i: row = mt*256 + fm*32 + (l&31), k-int32 = kt*32 + ks*16 + (l>>5)*8
__global__ void repack_a(const int* __restrict__ in, uint4* __restrict__ out) {
  int i = blockIdx.x * 256 + threadIdx.x;      // 2,097,152 total
  int l = i & 63;
  int u = (i >> 6) & 15;
  int tile = i >> 10;                          // mt*64 + kt
  int row = (tile >> 6) * 256 + (u >> 1) * 32 + (l & 31);
  int w0  = (tile & 63) * 32 + (u & 1) * 16 + (l >> 5) * 8;
  const int4* p = (const int4*)(in + (size_t)row * KP_ + w0);
  int4 a = p[0], b = p[1];
  uint4 o;
  o.x = nib2(a.x) | (nib2(a.y) << 16);
  o.y = nib2(a.z) | (nib2(a.w) << 16);
  o.z = nib2(b.x) | (nib2(b.y) << 16);
  o.w = nib2(b.z) | (nib2(b.w) << 16);
  out[i] = o;
}

// ---- repack B: [nt(32)][kt(64)][fn(4)][ks(2)][lane(64)][16B] ----
__global__ void repack_b(const int* __restrict__ in, uint4* __restrict__ out) {
  int i = blockIdx.x * 256 + threadIdx.x;      // 1,048,576 total
  int l = i & 63;
  int u = (i >> 6) & 7;
  int tile = i >> 9;                           // nt*64 + kt
  int row = (tile >> 6) * 128 + (u >> 1) * 32 + (l & 31);
  int w0  = (tile & 63) * 32 + (u & 1) * 16 + (l >> 5) * 8;
  const int4* p = (const int4*)(in + (size_t)row * KP_ + w0);
  int4 a = p[0], b = p[1];
  uint4 o;
  o.x = nib2(a.x) | (nib2(a.y) << 16);
  o.y = nib2(a.z) | (nib2(a.w) << 16);
  o.z = nib2(b.x) | (nib2(b.y) << 16);
  o.w = nib2(b.z) | (nib2(b.w) << 16);
  out[i] = o;
}

// ---- f32 -> bf16 (RNE) ----
__device__ __forceinline__ unsigned short f2b(float x) {
  unsigned u = __float_as_uint(x);
  return (unsigned short)((u + 0x7FFFu + ((u >> 16) & 1u)) >> 16);
}

__global__ void f2bf4(const float* __restrict__ in, unsigned short* __restrict__ out, int n4) {
  int stride = gridDim.x * blockDim.x;
  for (int i = blockIdx.x * blockDim.x + threadIdx.x; i < n4; i += stride) {
    float4 f = ((const float4*)in)[i];
    ushort4 o;
    o.x = f2b(f.x); o.y = f2b(f.y); o.z = f2b(f.z); o.w = f2b(f.w);
    ((ushort4*)out)[i] = o;
  }
}

// ---- main GEMM ----
__global__ __launch_bounds__(256, 2) void gemm_w4a4(
    const char* __restrict__ x8t, const char* __restrict__ w8t,
    const unsigned short* __restrict__ xrb, const unsigned short* __restrict__ wob,
    const float* __restrict__ xscale, const float* __restrict__ wscale,
    const float* __restrict__ bias, float* __restrict__ out)
{
  __shared__ __align__(16) char lds[3 * BUF_SZ];   // 72 KiB -> 2 blocks/CU

  const int t  = threadIdx.x;
  const int w  = t >> 6;           // wave 0..3
  const int l  = t & 63;
  const int lr = l & 31;           // row/col within 32-frag
  const int lh = l >> 5;           // k-half within frag

  const int wr = w >> 1;           // 0..1 -> 128-row half
  const int wc = w & 1;            // 0..1 -> 64-col half

  const int swz = (blockIdx.x & 7) * (GRID / 8) + (blockIdx.x >> 3);
  const int mt = swz & 31, ntile = swz >> 5;
  const int m0 = mt * BM, n0 = ntile * BN;

  const char* aT = x8t + (size_t)mt * NT * A_TILE;
  const char* bT = w8t + (size_t)ntile * NT * B_TILE;

  // wave w stages A granules {w, w+4, w+8, w+12} and B granules {w, w+4}
#define STAGE(tile, buf)                                                      \
  { const char* sa = aT + (size_t)(tile) * A_TILE + (w << 10) + (l << 4);     \
    char* da = lds + (buf) * BUF_SZ + (w << 10);                              \
    gload16(sa, da);                gload16(sa + 4096, da + 4096);            \
    gload16(sa + 8192, da + 8192); gload16(sa + 12288, da + 12288);           \
    const char* sb = bT + (size_t)(tile) * B_TILE + (w << 10) + (l << 4);     \
    char* db = lds + (buf) * BUF_SZ + A_TILE + (w << 10);                     \
    gload16(sb, db); gload16(sb + 4096, db + 4096); }
#define FENCE asm volatile("" ::: "memory")

  i32x16 acc[4][2] = {};

  // prologue: tiles 0,1 staged (12 loads/wave); wait tile 0 (6 younger remain)
  STAGE(0, 0)
  STAGE(1, 1)
  asm volatile("s_waitcnt vmcnt(6)" ::: "memory");
  __builtin_amdgcn_s_barrier();
  FENCE;

  int cur = 0;
  for (int kt = 0; kt < NT; ++kt) {
    const char* Ab = lds + cur * BUF_SZ;
    const char* Bb = Ab + A_TILE;

    i32x4 af[4][2], bf[2][2];
    #pragma unroll
    for (int mi = 0; mi < 4; ++mi)
      #pragma unroll
      for (int ks = 0; ks < 2; ++ks)
        af[mi][ks] = *(const i32x4*)(Ab + (((wr * 4 + mi) * 2 + ks) << 10) + (l << 4));
    #pragma unroll
    for (int ni = 0; ni < 2; ++ni)
      #pragma unroll
      for (int ks = 0; ks < 2; ++ks)
        bf[ni][ks] = *(const i32x4*)(Bb + (((wc * 2 + ni) * 2 + ks) << 10) + (l << 4));

    int nbuf = cur + 2; if (nbuf >= 3) nbuf -= 3;
    if (kt < NT - 2) {
      STAGE(kt + 2, nbuf)
      // outstanding: kt+1 (6) + kt+2 (6); keep 6 -> kt+1 landed for next iter
      asm volatile("s_waitcnt vmcnt(6)" ::: "memory");
    } else {
      asm volatile("s_waitcnt vmcnt(0)" ::: "memory");
    }
    __builtin_amdgcn_s_barrier();
    FENCE;

    __builtin_amdgcn_s_setprio(1);
    #pragma unroll
    for (int ks = 0; ks < 2; ++ks)
      #pragma unroll
      for (int mi = 0; mi < 4; ++mi)
        #pragma unroll
        for (int ni = 0; ni < 2; ++ni)
          acc[mi][ni] = __builtin_amdgcn_mfma_i32_32x32x32_i8(
              af[mi][ks], bf[ni][ks], acc[mi][ni], 0, 0, 0);
    __builtin_amdgcn_s_setprio(0);

    cur = cur + 1; if (cur >= 3) cur -= 3;
  }

  // ---- epilogue: dequant + bias + rank-32 outlier via 32x32x16 bf16 MFMA ----
  // B-operand frags (shared across mi): wo[col][k], col=lr, k=lh*8..+7 (+16)
  bf16x8 br0[2], br1[2];
  float swv[2], bv[2];
  #pragma unroll
  for (int ni = 0; ni < 2; ++ni) {
    int cg = n0 + wc * 64 + ni * 32 + lr;
    const unsigned short* pw = wob + (size_t)cg * R_;
    br0[ni] = *(const bf16x8*)(pw + lh * 8);
    br1[ni] = *(const bf16x8*)(pw + 16 + lh * 8);
    swv[ni] = wscale[cg];
    bv[ni]  = bias[cg];
  }

  #pragma unroll
  for (int mi = 0; mi < 4; ++mi) {
    const int rbase = m0 + wr * 128 + mi * 32;
    // x_scale for this 32-row frag: row(r) = (r&3) + 8*(r>>2) + 4*lh
    f32x4 sxg[4];
    #pragma unroll
    for (int g = 0; g < 4; ++g)
      sxg[g] = *(const f32x4*)(xscale + rbase + g * 8 + 4 * lh);
    const unsigned short* px = xrb + (size_t)(rbase + lr) * R_;
    bf16x8 ar0 = *(const bf16x8*)(px + lh * 8);
    bf16x8 ar1 = *(const bf16x8*)(px + 16 + lh * 8);

    #pragma unroll
    for (int ni = 0; ni < 2; ++ni) {
      f32x16 c = {};
      c = __builtin_amdgcn_mfma_f32_32x32x16_bf16(ar0, br0[ni], c, 0, 0, 0);
      c = __builtin_amdgcn_mfma_f32_32x32x16_bf16(ar1, br1[ni], c, 0, 0, 0);
      const int cg = n0 + wc * 64 + ni * 32 + lr;
      #pragma unroll
      for (int r = 0; r < 16; ++r) {
        int row = rbase + (r & 3) + 8 * (r >> 2) + 4 * lh;
        out[(size_t)row * N_ + cg] =
            (float)acc[mi][ni][r] * sxg[r >> 2][r & 3] * swv[ni] + c[r] + bv[ni];
      }
    }
  }
}

extern "C" void kernel_launch(void* const* d_in, const int* in_sizes, int n_in,
                              void* d_out, int out_size, void* d_ws, size_t ws_size,
                              hipStream_t stream) {
  const int*   x_quant   = (const int*)d_in[0];
  const float* x_scale   = (const float*)d_in[1];
  const int*   weight    = (const int*)d_in[2];
  const float* w_scales  = (const float*)d_in[3];
  const float* bias      = (const float*)d_in[4];
  const float* x_r       = (const float*)d_in[5];
  const float* w_outlier = (const float*)d_in[6];
  float* out = (float*)d_out;

  char* ws = (char*)d_ws;
  char*           x8t = ws;                                       // 32 MiB tiled
  char*           w8t = ws + (size_t)M_ * K_;                     // 16 MiB tiled
  unsigned short* xrb = (unsigned short*)(ws + (size_t)M_ * K_ + (size_t)N_ * K_);
  unsigned short* wob = xrb + (size_t)M_ * R_;

  repack_a<<<(M_ * K_ / 16) / 256, 256, 0, stream>>>(x_quant, (uint4*)x8t);
  repack_b<<<(N_ * K_ / 16) / 256, 256, 0, stream>>>(weight,  (uint4*)w8t);
  f2bf4<<<256, 256, 0, stream>>>(x_r, xrb, M_ * R_ / 4);
  f2bf4<<<128, 256, 0, stream>>>(w_outlier, wob, N_ * R_ / 4);

  gemm_w4a4<<<GRID, 256, 0, stream>>>(
      x8t, w8t, xrb, wob, x_scale, w_scales, bias, out);
}

// Round 5
// 196.496 us; speedup vs baseline: 1.0303x; 1.0303x over previous
//
#include <hip/hip_runtime.h>

// QuantLinearW4A4Tl: M=8192, K=4096, N=4096, R=32
#define M_ 8192
#define K_ 4096
#define N_ 4096
#define R_ 32
#define KP_ (K_ / 2)

// GEMM: 256x128 block, BK=64 i8, 4 waves (2x2) of 128x64, mfma 32x32x32.
// A: 3-deep LDS pipeline (48 KiB static). B: global->VGPR double-buffered
// (L2-hot panels; no LDS port use, no barrier dependence). NT stores keep
// operands L3-resident.
#define BM 256
#define BN 128
#define BK 64
#define NT 64
#define A_TILE 16384          // BM*BK
#define B_TILE 8192           // BN*BK (tiled image granularity)
#define GRID ((M_ / BM) * (N_ / BN))   // 1024

typedef __attribute__((ext_vector_type(4)))  int    i32x4;
typedef __attribute__((ext_vector_type(16))) int    i32x16;
typedef __attribute__((ext_vector_type(4)))  float  f32x4;
typedef __attribute__((ext_vector_type(16))) float  f32x16;
typedef __attribute__((ext_vector_type(8)))  __bf16 bf16x8;

__device__ __forceinline__ void gload16(const void* g, void* l) {
  __builtin_amdgcn_global_load_lds(
      (const __attribute__((address_space(1))) unsigned int*)g,
      (__attribute__((address_space(3))) unsigned int*)l, 16, 0, 0);
}

__device__ __forceinline__ unsigned nib2(int b) {
  unsigned lo = (unsigned)(((b & 15) ^ 8) - 8) & 0xFFu;
  unsigned hi = (unsigned)((((b >> 4) & 15) ^ 8) - 8) & 0xFFu;
  return lo | (hi << 8);
}

// ---- repack A: granule image [mt(32)][kt(64)][fm(8)][ks(2)][lane(64)][16B] ----
__global__ void repack_a(const int* __restrict__ in, uint4* __restrict__ out) {
  int i = blockIdx.x * 256 + threadIdx.x;
  int l = i & 63;
  int u = (i >> 6) & 15;
  int tile = i >> 10;                          // mt*64 + kt
  int row = (tile >> 6) * 256 + (u >> 1) * 32 + (l & 31);
  int w0  = (tile & 63) * 32 + (u & 1) * 16 + (l >> 5) * 8;
  const int4* p = (const int4*)(in + (size_t)row * KP_ + w0);
  int4 a = p[0], b = p[1];
  uint4 o;
  o.x = nib2(a.x) | (nib2(a.y) << 16);
  o.y = nib2(a.z) | (nib2(a.w) << 16);
  o.z = nib2(b.x) | (nib2(b.y) << 16);
  o.w = nib2(b.z) | (nib2(b.w) << 16);
  out[i] = o;
}

// ---- repack B: [nt(32)][kt(64)][fn(4)][ks(2)][lane(64)][16B] ----
__global__ void repack_b(const int* __restrict__ in, uint4* __restrict__ out) {
  int i = blockIdx.x * 256 + threadIdx.x;
  int l = i & 63;
  int u = (i >> 6) & 7;
  int tile = i >> 9;                           // nt*64 + kt
  int row = (tile >> 6) * 128 + (u >> 1) * 32 + (l & 31);
  int w0  = (tile & 63) * 32 + (u & 1) * 16 + (l >> 5) * 8;
  const int4* p = (const int4*)(in + (size_t)row * KP_ + w0);
  int4 a = p[0], b = p[1];
  uint4 o;
  o.x = nib2(a.x) | (nib2(a.y) << 16);
  o.y = nib2(a.z) | (nib2(a.w) << 16);
  o.z = nib2(b.x) | (nib2(b.y) << 16);
  o.w = nib2(b.z) | (nib2(b.w) << 16);
  out[i] = o;
}

// ---- f32 -> bf16 (RNE) ----
__device__ __forceinline__ unsigned short f2b(float x) {
  unsigned u = __float_as_uint(x);
  return (unsigned short)((u + 0x7FFFu + ((u >> 16) & 1u)) >> 16);
}

__global__ void f2bf4(const float* __restrict__ in, unsigned short* __restrict__ out, int n4) {
  int stride = gridDim.x * blockDim.x;
  for (int i = blockIdx.x * blockDim.x + threadIdx.x; i < n4; i += stride) {
    float4 f = ((const float4*)in)[i];
    ushort4 o;
    o.x = f2b(f.x); o.y = f2b(f.y); o.z = f2b(f.z); o.w = f2b(f.w);
    ((ushort4*)out)[i] = o;
  }
}

// ---- main GEMM ----
__global__ __launch_bounds__(256, 2) void gemm_w4a4(
    const char* __restrict__ x8t, const char* __restrict__ w8t,
    const unsigned short* __restrict__ xrb, const unsigned short* __restrict__ wob,
    const float* __restrict__ xscale, const float* __restrict__ wscale,
    const float* __restrict__ bias, float* __restrict__ out)
{
  __shared__ __align__(16) char lds[3 * A_TILE];   // 48 KiB, A only

  const int t  = threadIdx.x;
  const int w  = t >> 6;
  const int l  = t & 63;
  const int lr = l & 31;
  const int lh = l >> 5;
  const int wr = w >> 1;           // 0..1 -> 128-row half
  const int wc = w & 1;            // 0..1 -> 64-col half

  const int swz = (blockIdx.x & 7) * (GRID / 8) + (blockIdx.x >> 3);
  const int mt = swz & 31, ntile = swz >> 5;
  const int m0 = mt * BM, n0 = ntile * BN;

  const char* aT = x8t + (size_t)mt * NT * A_TILE;
  const char* bT = w8t + (size_t)ntile * NT * B_TILE;
  // wave's 4 B granules per tile start at bT + kt*8192 + wc*4096
  const char* bW = bT + (size_t)wc * 4096 + (l << 4);

#define STAGE_A(tile, buf)                                                    \
  { const char* sa = aT + (size_t)(tile) * A_TILE + (w << 10) + (l << 4);     \
    char* da = lds + (buf) * A_TILE + (w << 10);                              \
    gload16(sa, da);               gload16(sa + 4096, da + 4096);             \
    gload16(sa + 8192, da + 8192); gload16(sa + 12288, da + 12288); }
#define FENCE asm volatile("" ::: "memory")

#define LOADB(KT, DST)                                                        \
  { const char* sb = bW + (size_t)(KT) * B_TILE;                              \
    DST[0] = *(const i32x4*)(sb);        DST[1] = *(const i32x4*)(sb + 1024); \
    DST[2] = *(const i32x4*)(sb + 2048); DST[3] = *(const i32x4*)(sb + 3072); }

  // one sub-iteration: compute tile KT from LDS buf `cur` + B regs BUSE,
  // while loading B(KT+1)->BLOAD and staging A(KT+2).
#define ITER(KT, BUSE, BLOAD)                                                 \
  {                                                                           \
    const char* Ab = lds + cur * A_TILE;                                      \
    if ((KT) < NT - 1) LOADB((KT) + 1, BLOAD)                                 \
    int nb = cur + 2; if (nb >= 3) nb -= 3;                                   \
    if ((KT) < NT - 2) STAGE_A((KT) + 2, nb)                                  \
    FENCE;                                                                    \
    i32x4 af[4][2];                                                           \
    _Pragma("unroll")                                                         \
    for (int mi = 0; mi < 4; ++mi)                                            \
      _Pragma("unroll")                                                       \
      for (int ks = 0; ks < 2; ++ks)                                          \
        af[mi][ks] = *(const i32x4*)(Ab + (((wr * 4 + mi) * 2 + ks) << 10) + (l << 4)); \
    __builtin_amdgcn_s_setprio(1);                                            \
    _Pragma("unroll")                                                         \
    for (int ks = 0; ks < 2; ++ks)                                            \
      _Pragma("unroll")                                                       \
      for (int mi = 0; mi < 4; ++mi)                                          \
        _Pragma("unroll")                                                     \
        for (int ni = 0; ni < 2; ++ni)                                        \
          acc[mi][ni] = __builtin_amdgcn_mfma_i32_32x32x32_i8(                \
              af[mi][ks], BUSE[ni * 2 + ks], acc[mi][ni], 0, 0, 0);           \
    __builtin_amdgcn_s_setprio(0);                                            \
    FENCE;                                                                    \
    if ((KT) < NT - 2)      asm volatile("s_waitcnt vmcnt(8)" ::: "memory");  \
    else if ((KT) == NT - 2) asm volatile("s_waitcnt vmcnt(4)" ::: "memory"); \
    if ((KT) < NT - 1) { __builtin_amdgcn_s_barrier(); FENCE; }               \
    cur = cur + 1; if (cur >= 3) cur -= 3;                                    \
  }

  i32x16 acc[4][2] = {};
  i32x4 b0[4], b1[4];

  // prologue: A(0)->buf0, A(1)->buf1, B(0)->b0; wait A(0) (8 younger remain)
  STAGE_A(0, 0)
  STAGE_A(1, 1)
  LOADB(0, b0)
  asm volatile("s_waitcnt vmcnt(8)" ::: "memory");
  __builtin_amdgcn_s_barrier();
  FENCE;

  int cur = 0;
  for (int kt = 0; kt < NT; kt += 2) {
    ITER(kt, b0, b1)
    ITER(kt + 1, b1, b0)
  }

  // ---- epilogue: dequant + bias + rank-32 outlier via 32x32x16 bf16 MFMA ----
  bf16x8 br0[2], br1[2];
  float swv[2], bv[2];
  #pragma unroll
  for (int ni = 0; ni < 2; ++ni) {
    int cg = n0 + wc * 64 + ni * 32 + lr;
    const unsigned short* pw = wob + (size_t)cg * R_;
    br0[ni] = *(const bf16x8*)(pw + lh * 8);
    br1[ni] = *(const bf16x8*)(pw + 16 + lh * 8);
    swv[ni] = wscale[cg];
    bv[ni]  = bias[cg];
  }

  #pragma unroll
  for (int mi = 0; mi < 4; ++mi) {
    const int rbase = m0 + wr * 128 + mi * 32;
    f32x4 sxg[4];
    #pragma unroll
    for (int g = 0; g < 4; ++g)
      sxg[g] = *(const f32x4*)(xscale + rbase + g * 8 + 4 * lh);
    const unsigned short* px = xrb + (size_t)(rbase + lr) * R_;
    bf16x8 ar0 = *(const bf16x8*)(px + lh * 8);
    bf16x8 ar1 = *(const bf16x8*)(px + 16 + lh * 8);

    #pragma unroll
    for (int ni = 0; ni < 2; ++ni) {
      f32x16 c = {};
      c = __builtin_amdgcn_mfma_f32_32x32x16_bf16(ar0, br0[ni], c, 0, 0, 0);
      c = __builtin_amdgcn_mfma_f32_32x32x16_bf16(ar1, br1[ni], c, 0, 0, 0);
      const int cg = n0 + wc * 64 + ni * 32 + lr;
      #pragma unroll
      for (int r = 0; r < 16; ++r) {
        int row = rbase + (r & 3) + 8 * (r >> 2) + 4 * lh;
        float v = (float)acc[mi][ni][r] * sxg[r >> 2][r & 3] * swv[ni] + c[r] + bv[ni];
        __builtin_nontemporal_store(v, &out[(size_t)row * N_ + cg]);
      }
    }
  }
}

extern "C" void kernel_launch(void* const* d_in, const int* in_sizes, int n_in,
                              void* d_out, int out_size, void* d_ws, size_t ws_size,
                              hipStream_t stream) {
  const int*   x_quant   = (const int*)d_in[0];
  const float* x_scale   = (const float*)d_in[1];
  const int*   weight    = (const int*)d_in[2];
  const float* w_scales  = (const float*)d_in[3];
  const float* bias      = (const float*)d_in[4];
  const float* x_r       = (const float*)d_in[5];
  const float* w_outlier = (const float*)d_in[6];
  float* out = (float*)d_out;

  char* ws = (char*)d_ws;
  char*           x8t = ws;
  char*           w8t = ws + (size_t)M_ * K_;
  unsigned short* xrb = (unsigned short*)(ws + (size_t)M_ * K_ + (size_t)N_ * K_);
  unsigned short* wob = xrb + (size_t)M_ * R_;

  repack_a<<<(M_ * K_ / 16) / 256, 256, 0, stream>>>(x_quant, (uint4*)x8t);
  repack_b<<<(N_ * K_ / 16) / 256, 256, 0, stream>>>(weight,  (uint4*)w8t);
  f2bf4<<<256, 256, 0, stream>>>(x_r, xrb, M_ * R_ / 4);
  f2bf4<<<128, 256, 0, stream>>>(w_outlier, wob, N_ * R_ / 4);

  gemm_w4a4<<<GRID, 256, 0, stream>>>(
      x8t, w8t, xrb, wob, x_scale, w_scales, bias, out);
}